// Round 1
// baseline (1258.923 us; speedup 1.0000x reference)
//
#include <hip/hip_runtime.h>
#include <hip/hip_bf16.h>

// Problem constants
#define NUM_USERS 8192
#define NUM_ITEMS 32768
#define FEAT 129
#define KP 160            // K padded to multiple of 32 (5 MFMA k-steps)
#define NOUT 32768        // output row stride (= NUM_ITEMS)

typedef _Float16 f16x8 __attribute__((ext_vector_type(8)));
typedef float    f32x4 __attribute__((ext_vector_type(4)));

// ---------------------------------------------------------------------------
// Pack: h (40960 x 129 fp32) -> A (8192 x 160 fp16, col0 negated), B (32768 x 160 fp16)
// Zero-pad cols [129,160). Re-written every launch (ws is re-poisoned).
// ---------------------------------------------------------------------------
__global__ void pack_kernel(const float* __restrict__ h,
                            _Float16* __restrict__ apack,
                            _Float16* __restrict__ bpack) {
    int idx = blockIdx.x * blockDim.x + threadIdx.x;   // 0 .. 40960*160-1
    int row = idx / KP;
    int col = idx - row * KP;
    float v = 0.0f;
    if (col < FEAT) v = h[(size_t)row * FEAT + col];
    if (row < NUM_USERS) {
        if (col == 0) v = -v;                           // signs[0] = -1 folded into A
        apack[(size_t)row * KP + col] = (_Float16)v;
    } else {
        bpack[(size_t)(row - NUM_USERS) * KP + col] = (_Float16)v;
    }
}

// ---------------------------------------------------------------------------
// GEMM + arccosh^2 epilogue. 128x128 tile per block (256 threads = 4 waves,
// each wave a 64x64 subtile = 4x4 MFMA 16x16x32_f16 fragments).
// m97 structure: global_load_lds width-16 staging, 2-barrier K loop.
// ---------------------------------------------------------------------------
__global__ __launch_bounds__(256) void gemm_arccosh_kernel(
        const _Float16* __restrict__ A,   // M x KP, row-major
        const _Float16* __restrict__ B,   // N x KP, row-major (B^T form)
        float* __restrict__ out) {        // M x N
    __shared__ __align__(16) _Float16 As[128 * 32];   // 8 KB
    __shared__ __align__(16) _Float16 Bs[128 * 32];   // 8 KB

    const int t  = threadIdx.x;
    const int l  = t & 63;
    const int w  = t >> 6;
    const int wm = (w >> 1) * 64;     // wave row offset in tile
    const int wn = (w & 1)  * 64;     // wave col offset in tile
    const int q  = l >> 4;            // quad id 0..3
    const int lm = l & 15;

    const int mBase = blockIdx.y * 128;
    const int nBase = blockIdx.x * 128;

    f32x4 acc[4][4];
#pragma unroll
    for (int i = 0; i < 4; i++)
#pragma unroll
        for (int j = 0; j < 4; j++) acc[i][j] = (f32x4){0.f, 0.f, 0.f, 0.f};

    for (int k0 = 0; k0 < KP; k0 += 32) {
        // Stage A and B tiles: 128 rows x 32 halves (64 B/row), 8 KB each.
        // 256 threads x 16 B x 2 iters covers one tile. LDS dest is
        // wave-uniform base + lane*16 => layout must be lane-contiguous: it is
        // (byte offset o = i*4096 + t*16 maps to row=o/64, 16B-chunk=(o/16)&3).
#pragma unroll
        for (int i = 0; i < 2; i++) {
            const int o   = i * 4096 + t * 16;     // byte offset in tile
            const int row = o >> 6;
            const int kc  = (o >> 4) & 3;
            const _Float16* ga = A + (size_t)(mBase + row) * KP + k0 + kc * 8;
            __builtin_amdgcn_global_load_lds(
                (const __attribute__((address_space(1))) unsigned int*)ga,
                (__attribute__((address_space(3))) unsigned int*)((char*)As + o),
                16, 0, 0);
            const _Float16* gb = B + (size_t)(nBase + row) * KP + k0 + kc * 8;
            __builtin_amdgcn_global_load_lds(
                (const __attribute__((address_space(1))) unsigned int*)gb,
                (__attribute__((address_space(3))) unsigned int*)((char*)Bs + o),
                16, 0, 0);
        }
        __syncthreads();

        // LDS -> fragments: A[m = lane&15][k = q*8 + j], same for B (N x K).
        f16x8 af[4], bf[4];
#pragma unroll
        for (int im = 0; im < 4; im++)
            af[im] = *(const f16x8*)&As[(wm + im * 16 + lm) * 32 + q * 8];
#pragma unroll
        for (int in = 0; in < 4; in++)
            bf[in] = *(const f16x8*)&Bs[(wn + in * 16 + lm) * 32 + q * 8];

#pragma unroll
        for (int im = 0; im < 4; im++)
#pragma unroll
            for (int in = 0; in < 4; in++)
                acc[im][in] = __builtin_amdgcn_mfma_f32_16x16x32_f16(
                    af[im], bf[in], acc[im][in], 0, 0, 0);
        __syncthreads();
    }

    // Epilogue: C/D layout col = lane&15 (n), row = q*4 + reg (m).
    // sqdist = min(arccosh(max(-prod, 1+eps))^2, 50); out = -sqdist.
#pragma unroll
    for (int im = 0; im < 4; im++) {
#pragma unroll
        for (int in = 0; in < 4; in++) {
            const int n = nBase + wn + in * 16 + lm;
#pragma unroll
            for (int r = 0; r < 4; r++) {
                const int m = mBase + wm + im * 16 + q * 4 + r;
                const float prod  = acc[im][in][r];
                const float theta = fmaxf(-prod, 1.0f + 1e-7f);
                const float t2    = fmaxf(__builtin_fmaf(theta, theta, -1.0f), 0.0f);
                const float ac    = __logf(theta + __builtin_sqrtf(t2));
                const float s     = fminf(ac * ac, 50.0f);
                out[(size_t)m * NOUT + n] = -s;
            }
        }
    }
}

extern "C" void kernel_launch(void* const* d_in, const int* in_sizes, int n_in,
                              void* d_out, int out_size, void* d_ws, size_t ws_size,
                              hipStream_t stream) {
    const float* h = (const float*)d_in[0];
    float* out = (float*)d_out;

    _Float16* apack = (_Float16*)d_ws;                       // 8192*160*2  = 2.62 MB
    _Float16* bpack = apack + (size_t)NUM_USERS * KP;        // 32768*160*2 = 10.49 MB

    const int total = (NUM_USERS + NUM_ITEMS) * KP;          // 6,553,600 (exact /256)
    pack_kernel<<<total / 256, 256, 0, stream>>>(h, apack, bpack);

    dim3 grid(NUM_ITEMS / 128, NUM_USERS / 128);             // 256 x 64 blocks
    gemm_arccosh_kernel<<<grid, 256, 0, stream>>>(apack, bpack, out);
}